// Round 3
// baseline (370.541 us; speedup 1.0000x reference)
//
#include <hip/hip_runtime.h>
#include <hip/hip_bf16.h>
#include <math.h>

#define AS1 __attribute__((address_space(1)))
#define AS3 __attribute__((address_space(3)))

typedef __bf16  bf16x8 __attribute__((ext_vector_type(8)));
typedef float   f32x4  __attribute__((ext_vector_type(4)));
typedef __hip_bfloat16 bf16;

__device__ __forceinline__ void gload_lds16(const void* g, void* l) {
  __builtin_amdgcn_global_load_lds((const AS1 void*)g, (AS3 void*)l, 16, 0, 0);
}

// ---------------- weight conversion f32 -> bf16 ----------------
// layout in dst: qkv_w[196608] | proj_w[65536] | mlp_w1[262144] | mlp_w2[262144]
__global__ __launch_bounds__(256) void k_conv_weights(
    const float* __restrict__ qkvw, const float* __restrict__ projw,
    const float* __restrict__ w1, const float* __restrict__ w2,
    bf16* __restrict__ dst)
{
  int i = blockIdx.x * 256 + threadIdx.x;   // grid covers exactly 786432
  float v;
  if (i < 196608)       v = qkvw[i];
  else if (i < 262144)  v = projw[i - 196608];
  else if (i < 524288)  v = w1[i - 262144];
  else                  v = w2[i - 524288];
  dst[i] = __float2bfloat16(v);
}

// ---------------- rel-pos bias table: btab[h][n][m] ----------------
__global__ __launch_bounds__(256) void k_build_btab(
    const float* __restrict__ rel_bias, float* __restrict__ btab)
{
  int i = blockIdx.x * 256 + threadIdx.x;   // 32768
  int h = i >> 12, r = i & 4095, n = r >> 6, m = r & 63;
  int idx = ((n >> 3) - (m >> 3) + 7) * 15 + ((n & 7) - (m & 7) + 7);
  btab[i] = rel_bias[idx * 8 + h];
}

// ---------------- LN1 + roll(-4,-4) + window partition, f32 -> bf16 ----------------
__global__ __launch_bounds__(256) void k_ln1_window(
    const float* __restrict__ x, const float* __restrict__ sc,
    const float* __restrict__ bi, bf16* __restrict__ hout)
{
  int t = blockIdx.x * 4 + (threadIdx.x >> 6);
  int lane = threadIdx.x & 63;
  int win = t >> 6, nn = t & 63;
  int b = win >> 6, ww = win & 63;
  int ry = ((ww >> 3) << 3) + (nn >> 3);
  int rx = ((ww & 7) << 3) + (nn & 7);
  int sy = (ry + 4) & 63, sx = (rx + 4) & 63;
  const float* src = x + ((size_t)(((b << 6) + sy) << 6) + sx) * 256;
  f32x4 v = *(const f32x4*)(src + lane * 4);
  float s = v[0] + v[1] + v[2] + v[3];
  #pragma unroll
  for (int o = 1; o < 64; o <<= 1) s += __shfl_xor(s, o);
  float mu = s * (1.0f / 256.0f);
  float d0 = v[0]-mu, d1 = v[1]-mu, d2 = v[2]-mu, d3 = v[3]-mu;
  float q = d0*d0 + d1*d1 + d2*d2 + d3*d3;
  #pragma unroll
  for (int o = 1; o < 64; o <<= 1) q += __shfl_xor(q, o);
  float rstd = rsqrtf(q * (1.0f / 256.0f) + 1e-5f);
  int c = lane * 4;
  union { bf16 h[4]; uint2 u; } pk;
  pk.h[0] = __float2bfloat16(d0 * rstd * sc[c+0] + bi[c+0]);
  pk.h[1] = __float2bfloat16(d1 * rstd * sc[c+1] + bi[c+1]);
  pk.h[2] = __float2bfloat16(d2 * rstd * sc[c+2] + bi[c+2]);
  pk.h[3] = __float2bfloat16(d3 * rstd * sc[c+3] + bi[c+3]);
  *(uint2*)(hout + (size_t)t * 256 + c) = pk.u;
}

// ---------------- LN2 (pixel-major), f32 -> bf16 ----------------
__global__ __launch_bounds__(256) void k_ln2(
    const float* __restrict__ x1, const float* __restrict__ sc,
    const float* __restrict__ bi, bf16* __restrict__ out)
{
  int t = blockIdx.x * 4 + (threadIdx.x >> 6);
  int lane = threadIdx.x & 63;
  const float* src = x1 + (size_t)t * 256;
  f32x4 v = *(const f32x4*)(src + lane * 4);
  float s = v[0] + v[1] + v[2] + v[3];
  #pragma unroll
  for (int o = 1; o < 64; o <<= 1) s += __shfl_xor(s, o);
  float mu = s * (1.0f / 256.0f);
  float d0 = v[0]-mu, d1 = v[1]-mu, d2 = v[2]-mu, d3 = v[3]-mu;
  float q = d0*d0 + d1*d1 + d2*d2 + d3*d3;
  #pragma unroll
  for (int o = 1; o < 64; o <<= 1) q += __shfl_xor(q, o);
  float rstd = rsqrtf(q * (1.0f / 256.0f) + 1e-5f);
  int c = lane * 4;
  union { bf16 h[4]; uint2 u; } pk;
  pk.h[0] = __float2bfloat16(d0 * rstd * sc[c+0] + bi[c+0]);
  pk.h[1] = __float2bfloat16(d1 * rstd * sc[c+1] + bi[c+1]);
  pk.h[2] = __float2bfloat16(d2 * rstd * sc[c+2] + bi[c+2]);
  pk.h[3] = __float2bfloat16(d3 * rstd * sc[c+3] + bi[c+3]);
  *(uint2*)(out + (size_t)t * 256 + c) = pk.u;
}

// ---------------- generic GEMM: C[M,N] = A[M,K] @ Bw[N,K]^T + bias ----------------
// Swapped-operand MFMA: acc[m][n] holds per lane 4 consecutive cols of C at
// row (wr+m*16+l15), cols (wc+n*16+lh*4 .. +3).
// EPI 0: store bf16
// EPI 2: proj: remap token->pixel (inverse window + roll +4), += resid(x), f32 out
#define BM 128
#define BN 128
#define BKK 64

template<int EPI>
__global__ __launch_bounds__(256) void k_gemm_bt(
    const bf16* __restrict__ A, const bf16* __restrict__ Bw,
    const float* __restrict__ bias,
    float* __restrict__ Cf, bf16* __restrict__ Cb,
    const float* __restrict__ resid,
    int M, int N, int K)
{
  __shared__ __align__(16) char lds[BM*BKK*2 + BN*BKK*2];  // 16KB + 16KB
  char* ldsA = lds;
  char* ldsB = lds + BM*BKK*2;

  const int tid = threadIdx.x;
  const int wid = tid >> 6;
  const int lane = tid & 63;
  const int l15 = lane & 15, lh = lane >> 4;
  const int rowBase = blockIdx.y * BM;
  const int colBase = blockIdx.x * BN;
  const int wr = (wid >> 1) * 64;
  const int wc = (wid & 1) * 64;

  f32x4 acc[4][4];
  #pragma unroll
  for (int i = 0; i < 4; ++i)
    #pragma unroll
    for (int j = 0; j < 4; ++j) acc[i][j] = (f32x4){0.f,0.f,0.f,0.f};

  for (int k0 = 0; k0 < K; k0 += BKK) {
    #pragma unroll
    for (int i = 0; i < 4; ++i) {
      int chunk = i * 4 + wid;                     // 0..15, 1KB per wave-issue
      int off = (chunk * 64 + lane) * 16;          // byte offset in 16KB tile
      int r = off >> 7;                            // tile row (128B/row)
      int cb = off & 127;
      int csw = cb ^ ((r & 7) << 4);               // inverse-swizzled source col
      const char* gA = (const char*)(A + (size_t)(rowBase + r) * K + k0) + csw;
      gload_lds16(gA, ldsA + chunk * 1024);
      const char* gB = (const char*)(Bw + (size_t)(colBase + r) * K + k0) + csw;
      gload_lds16(gB, ldsB + chunk * 1024);
    }
    __syncthreads();
    #pragma unroll
    for (int kk = 0; kk < BKK / 32; ++kk) {
      bf16x8 af[4], bfr[4];
      int kb = kk * 64 + lh * 16;
      #pragma unroll
      for (int m = 0; m < 4; ++m) {
        int rA = wr + m * 16 + l15;
        af[m] = *(const bf16x8*)(ldsA + rA * 128 + (kb ^ ((rA & 7) << 4)));
        int rB = wc + m * 16 + l15;
        bfr[m] = *(const bf16x8*)(ldsB + rB * 128 + (kb ^ ((rB & 7) << 4)));
      }
      #pragma unroll
      for (int m = 0; m < 4; ++m)
        #pragma unroll
        for (int n = 0; n < 4; ++n)
          acc[m][n] = __builtin_amdgcn_mfma_f32_16x16x32_bf16(bfr[n], af[m], acc[m][n], 0, 0, 0);
    }
    __syncthreads();
  }

  #pragma unroll
  for (int m = 0; m < 4; ++m) {
    const int row = rowBase + wr + m * 16 + l15;
    size_t rowAddr;
    if (EPI == 2) {
      int win = row >> 6, nn = row & 63;
      int b = win >> 6, ww = win & 63;
      int ry = ((ww >> 3) << 3) + (nn >> 3);
      int rx = ((ww & 7) << 3) + (nn & 7);
      int fy = (ry + 4) & 63, fx = (rx + 4) & 63;
      rowAddr = ((size_t)(((b << 6) + fy) << 6) + fx) * 256;
    } else {
      rowAddr = (size_t)row * N;
    }
    #pragma unroll
    for (int n = 0; n < 4; ++n) {
      const int colb = colBase + wc + n * 16 + lh * 4;
      const f32x4 b4 = *(const f32x4*)(bias + colb);
      f32x4 v4;
      #pragma unroll
      for (int j = 0; j < 4; ++j) v4[j] = acc[m][n][j] + b4[j];
      if (EPI == 0) {
        union { bf16 h[4]; uint2 u; } pk;
        #pragma unroll
        for (int j = 0; j < 4; ++j) pk.h[j] = __float2bfloat16(v4[j]);
        *(uint2*)(Cb + rowAddr + colb) = pk.u;
      } else if (EPI == 2) {
        const f32x4 r4 = *(const f32x4*)(resid + rowAddr + colb);
        f32x4 o4;
        #pragma unroll
        for (int j = 0; j < 4; ++j) o4[j] = v4[j] + r4[j];
        *(f32x4*)(Cf + rowAddr + colb) = o4;
      }
    }
  }
}

// ---------------- fused MLP: x1 += GELU(ln2h @ W1^T + b1) @ W2^T + b2 ----------------
// A: ln2h [65536][256] bf16 ; W1 [1024][256] bf16 ; W2 [256][1024] bf16 (native)
// Per block: 128 rows. Loop 8 hidden-blocks of 128:
//   stage1: P = GELU(A @ W1_hb^T + b1)  (128x128, K=256) -> LDS bf16 swizzled
//   stage2: acc2(128x256 f32) += P @ W2[:,hb]^T          (K=128)
// Epilogue: x1 += acc2 + b2 (f32 RMW).
__global__ __launch_bounds__(256, 2) void k_mlp_fused(
    const bf16* __restrict__ A, const bf16* __restrict__ W1,
    const float* __restrict__ B1, const bf16* __restrict__ W2,
    const float* __restrict__ B2, float* __restrict__ X1)
{
  __shared__ __align__(16) char lds[65536];
  char* bufA = lds;            // 16KB (stage1 A) ; stage2: chunks 0..31 = W2 32KB
  char* bufB = lds + 16384;    // 16KB (stage1 W1)
  char* bufP = lds + 32768;    // 32KB P: 128 rows x 256B, XOR-swizzled

  const int tid = threadIdx.x, wid = tid >> 6, lane = tid & 63;
  const int l15 = lane & 15, lh = lane >> 4;
  const int rowBase = blockIdx.x * 128;
  const int wr = (wid >> 1) * 64;   // rows (stage1 & stage2)
  const int wh = (wid & 1) * 64;    // stage1 hidden cols
  const int wc = (wid & 1) * 128;   // stage2 out cols

  f32x4 acc2[4][8];
  #pragma unroll
  for (int m = 0; m < 4; ++m)
    #pragma unroll
    for (int n = 0; n < 8; ++n) acc2[m][n] = (f32x4){0.f,0.f,0.f,0.f};

  for (int hb = 0; hb < 8; ++hb) {
    // ---- stage 1: P = A @ W1_hb^T (K=256) ----
    f32x4 acc1[4][4];
    #pragma unroll
    for (int m = 0; m < 4; ++m)
      #pragma unroll
      for (int n = 0; n < 4; ++n) acc1[m][n] = (f32x4){0.f,0.f,0.f,0.f};

    for (int k0 = 0; k0 < 256; k0 += 64) {
      #pragma unroll
      for (int i = 0; i < 4; ++i) {
        int chunk = i * 4 + wid;
        int off = (chunk * 64 + lane) * 16;
        int r = off >> 7, cb = off & 127;
        int csw = cb ^ ((r & 7) << 4);
        gload_lds16((const char*)(A + (size_t)(rowBase + r) * 256 + k0) + csw,
                    bufA + chunk * 1024);
        gload_lds16((const char*)(W1 + (size_t)(hb * 128 + r) * 256 + k0) + csw,
                    bufB + chunk * 1024);
      }
      __syncthreads();
      #pragma unroll
      for (int kk = 0; kk < 2; ++kk) {
        bf16x8 af[4], wf[4];
        int kb = kk * 64 + lh * 16;
        #pragma unroll
        for (int m = 0; m < 4; ++m) {
          int rA = wr + m * 16 + l15;
          af[m] = *(const bf16x8*)(bufA + rA * 128 + (kb ^ ((rA & 7) << 4)));
          int rW = wh + m * 16 + l15;
          wf[m] = *(const bf16x8*)(bufB + rW * 128 + (kb ^ ((rW & 7) << 4)));
        }
        #pragma unroll
        for (int m = 0; m < 4; ++m)
          #pragma unroll
          for (int n = 0; n < 4; ++n)
            acc1[m][n] = __builtin_amdgcn_mfma_f32_16x16x32_bf16(wf[n], af[m], acc1[m][n], 0, 0, 0);
      }
      __syncthreads();
    }

    // ---- GELU + pack -> P LDS ----
    #pragma unroll
    for (int m = 0; m < 4; ++m) {
      int prow = wr + m * 16 + l15;
      #pragma unroll
      for (int n = 0; n < 4; ++n) {
        int hc0 = wh + n * 16 + lh * 4;
        const f32x4 b4 = *(const f32x4*)(B1 + hb * 128 + hc0);
        union { bf16 h[4]; uint2 u; } pk;
        #pragma unroll
        for (int j = 0; j < 4; ++j) {
          float v = acc1[m][n][j] + b4[j];
          // gelu(v) = v * sigmoid(1.59577 v + 0.0713548 v^3); exp folded to exp2
          float w = fmaf(v * v, 0.1029434f, 2.3022083f);
          float e = __builtin_amdgcn_exp2f(-v * w);
          float g = v * __builtin_amdgcn_rcpf(1.0f + e);
          pk.h[j] = __float2bfloat16(g);
        }
        *(uint2*)(bufP + prow * 256 + ((hc0 * 2) ^ ((prow & 7) << 4))) = pk.u;
      }
    }
    __syncthreads();

    // ---- stage 2: acc2 += P @ W2[:, hb*128 + ...]^T (K=128, two 64-steps) ----
    #pragma unroll
    for (int ks2 = 0; ks2 < 2; ++ks2) {
      #pragma unroll
      for (int i = 0; i < 8; ++i) {
        int chunk = i * 4 + wid;                   // 0..31 (32KB)
        int off = (chunk * 64 + lane) * 16;
        int r = off >> 7, cb = off & 127;
        int csw = cb ^ ((r & 7) << 4);
        gload_lds16((const char*)(W2 + (size_t)r * 1024 + hb * 128 + ks2 * 64) + csw,
                    lds + chunk * 1024);
      }
      __syncthreads();
      #pragma unroll
      for (int kk = 0; kk < 2; ++kk) {
        bf16x8 pf[4], w2f[8];
        int kb = kk * 64 + lh * 16;                // within 128B W2 rows
        int kp = ks2 * 128 + kb;                   // within 256B P rows
        #pragma unroll
        for (int m = 0; m < 4; ++m) {
          int rP = wr + m * 16 + l15;
          pf[m] = *(const bf16x8*)(bufP + rP * 256 + (kp ^ ((rP & 7) << 4)));
        }
        #pragma unroll
        for (int n = 0; n < 8; ++n) {
          int rW = wc + n * 16 + l15;
          w2f[n] = *(const bf16x8*)(lds + rW * 128 + (kb ^ ((rW & 7) << 4)));
        }
        #pragma unroll
        for (int m = 0; m < 4; ++m)
          #pragma unroll
          for (int n = 0; n < 8; ++n)
            acc2[m][n] = __builtin_amdgcn_mfma_f32_16x16x32_bf16(w2f[n], pf[m], acc2[m][n], 0, 0, 0);
      }
      __syncthreads();
    }
  }

  // ---- epilogue: x1 += acc2 + b2 ----
  #pragma unroll
  for (int m = 0; m < 4; ++m) {
    size_t rowAddr = (size_t)(rowBase + wr + m * 16 + l15) * 256;
    #pragma unroll
    for (int n = 0; n < 8; ++n) {
      int cb0 = wc + n * 16 + lh * 4;
      const f32x4 b4 = *(const f32x4*)(B2 + cb0);
      f32x4* p = (f32x4*)(X1 + rowAddr + cb0);
      f32x4 c = *p;
      #pragma unroll
      for (int j = 0; j < 4; ++j) c[j] += acc2[m][n][j] + b4[j];
      *p = c;
    }
  }
}

// ---------------- attention: 1 wave per (window, head) ----------------
__global__ __launch_bounds__(256) void k_attn(
    const bf16* __restrict__ qkv, const float* __restrict__ btab,
    bf16* __restrict__ outp)
{
  __shared__ __align__(16) char smem[71680];
  float* sb = (float*)smem;                        // 64*64 f32 bias for this head
  const int tid = threadIdx.x, wid = tid >> 6, lane = tid & 63;
  const int l15 = lane & 15, lh = lane >> 4;
  const int h = blockIdx.x >> 8;
  const int win = ((blockIdx.x & 255) << 2) + wid;
  const int tb = win << 6;
  char* plw = smem + 16384 + wid * 9216;           // P: 64 rows x 144B (72 bf16)
  char* vtw = smem + 16384 + 36864 + wid * 4608;   // Vt: 32 rows x 144B

  for (int i = tid; i < 4096; i += 256) sb[i] = btab[(h << 12) + i];
  __syncthreads();

  bf16x8 qf[4], kf[4];
  #pragma unroll
  for (int m = 0; m < 4; ++m) {
    size_t base = (size_t)(tb + m * 16 + l15) * 768 + h * 32 + lh * 8;
    qf[m] = *(const bf16x8*)(qkv + base);
    kf[m] = *(const bf16x8*)(qkv + base + 256);
  }
  f32x4 s[4][4];
  #pragma unroll
  for (int i = 0; i < 4; ++i)
    #pragma unroll
    for (int j = 0; j < 4; ++j) {
      s[i][j] = (f32x4){0.f,0.f,0.f,0.f};
      s[i][j] = __builtin_amdgcn_mfma_f32_16x16x32_bf16(qf[i], kf[j], s[i][j], 0, 0, 0);
    }

  #pragma unroll
  for (int it = 0; it < 32; ++it) {
    int idx = it * 64 + lane;
    int m = idx >> 5, d = idx & 31;
    bf16 vv = qkv[(size_t)(tb + m) * 768 + 512 + h * 32 + d];
    *(bf16*)(vtw + d * 144 + m * 2) = vv;
  }

  int ww = win & 63, wi = ww >> 3, wj = ww & 7;
  int labm[4];
  #pragma unroll
  for (int jf = 0; jf < 4; ++jf) {
    int m = jf * 16 + l15;
    int yy = wi * 8 + (m >> 3), xx = wj * 8 + (m & 7);
    labm[jf] = (yy < 56 ? 0 : (yy < 60 ? 1 : 2)) * 3 + (xx < 56 ? 0 : (xx < 60 ? 1 : 2));
  }
  float rsum[4][4];
  const float scale = 0.17677669529663687f;  // 1/sqrt(32)
  #pragma unroll
  for (int i = 0; i < 4; ++i) {
    #pragma unroll
    for (int j = 0; j < 4; ++j) {
      int n = i * 16 + lh * 4 + j;
      int yy = wi * 8 + (n >> 3), xx = wj * 8 + (n & 7);
      int labn = (yy < 56 ? 0 : (yy < 60 ? 1 : 2)) * 3 + (xx < 56 ? 0 : (xx < 60 ? 1 : 2));
      float vals[4]; float mx = -1e30f;
      #pragma unroll
      for (int jf = 0; jf < 4; ++jf) {
        int m = jf * 16 + l15;
        float v = s[i][jf][j] * scale + sb[(n << 6) + m];
        if (labn != labm[jf]) v -= 100.0f;
        vals[jf] = v; mx = fmaxf(mx, v);
      }
      #pragma unroll
      for (int o = 1; o < 16; o <<= 1) mx = fmaxf(mx, __shfl_xor(mx, o));
      float sum = 0.0f;
      #pragma unroll
      for (int jf = 0; jf < 4; ++jf) {
        float e = __expf(vals[jf] - mx);
        sum += e;
        *(bf16*)(plw + n * 144 + (jf * 16 + l15) * 2) = __float2bfloat16(e);
      }
      #pragma unroll
      for (int o = 1; o < 16; o <<= 1) sum += __shfl_xor(sum, o);
      rsum[i][j] = sum;
    }
  }
  __syncthreads();

  f32x4 o[4][2];
  #pragma unroll
  for (int i = 0; i < 4; ++i) { o[i][0] = (f32x4){0.f,0.f,0.f,0.f}; o[i][1] = (f32x4){0.f,0.f,0.f,0.f}; }
  #pragma unroll
  for (int kk = 0; kk < 2; ++kk) {
    bf16x8 pf[4], vf[2];
    #pragma unroll
    for (int i = 0; i < 4; ++i)
      pf[i] = *(const bf16x8*)(plw + (i * 16 + l15) * 144 + kk * 64 + lh * 16);
    #pragma unroll
    for (int df = 0; df < 2; ++df)
      vf[df] = *(const bf16x8*)(vtw + (df * 16 + l15) * 144 + kk * 64 + lh * 16);
    #pragma unroll
    for (int i = 0; i < 4; ++i)
      #pragma unroll
      for (int df = 0; df < 2; ++df)
        o[i][df] = __builtin_amdgcn_mfma_f32_16x16x32_bf16(pf[i], vf[df], o[i][df], 0, 0, 0);
  }
  #pragma unroll
  for (int i = 0; i < 4; ++i)
    #pragma unroll
    for (int df = 0; df < 2; ++df)
      #pragma unroll
      for (int j = 0; j < 4; ++j) {
        int n = i * 16 + lh * 4 + j;
        int d = df * 16 + l15;
        float v = o[i][df][j] / rsum[i][j];
        outp[(size_t)(tb + n) * 256 + h * 32 + d] = __float2bfloat16(v);
      }
}

// ---------------- launch ----------------
extern "C" void kernel_launch(void* const* d_in, const int* in_sizes, int n_in,
                              void* d_out, int out_size, void* d_ws, size_t ws_size,
                              hipStream_t stream) {
  (void)in_sizes; (void)n_in; (void)out_size; (void)ws_size;
  const float* x      = (const float*)d_in[0];
  const float* ln1_s  = (const float*)d_in[1];
  const float* ln1_b  = (const float*)d_in[2];
  const float* qkv_w  = (const float*)d_in[3];
  const float* qkv_b  = (const float*)d_in[4];
  const float* proj_w = (const float*)d_in[5];
  const float* proj_b = (const float*)d_in[6];
  const float* rel_b  = (const float*)d_in[7];
  const float* ln2_s  = (const float*)d_in[8];
  const float* ln2_b  = (const float*)d_in[9];
  const float* w1     = (const float*)d_in[10];
  const float* b1     = (const float*)d_in[11];
  const float* w2     = (const float*)d_in[12];
  const float* b2     = (const float*)d_in[13];

  char* ws = (char*)d_ws;
  bf16*  wqkv  = (bf16*)(ws + 0);               // 196608 el
  bf16*  wproj = wqkv + 196608;                 // 65536 el
  bf16*  wm1   = wqkv + 262144;                 // 262144 el
  bf16*  wm2   = wqkv + 524288;                 // 262144 el
  float* btab  = (float*)(ws + 1572864);        // 32768 f32
  bf16*  hbuf  = (bf16*)(ws + 2097152);         // 65536x256
  bf16*  qkvb  = (bf16*)(ws + 35651584);        // 65536x768
  bf16*  attnb = (bf16*)(ws + 136314880);       // 65536x256
  bf16*  ln2buf = hbuf;                         // reuse (h dead after QKV gemm)
  float* x1    = (float*)d_out;                 // residual lives in d_out

  k_conv_weights<<<3072, 256, 0, stream>>>(qkv_w, proj_w, w1, w2, wqkv);
  k_build_btab<<<128, 256, 0, stream>>>(rel_b, btab);
  k_ln1_window<<<16384, 256, 0, stream>>>(x, ln1_s, ln1_b, hbuf);
  k_gemm_bt<0><<<dim3(6, 512), 256, 0, stream>>>(hbuf, wqkv, qkv_b, nullptr, qkvb, nullptr, 65536, 768, 256);
  k_attn<<<2048, 256, 0, stream>>>(qkvb, btab, attnb);
  k_gemm_bt<2><<<dim3(2, 512), 256, 0, stream>>>(attnb, wproj, proj_b, x1, nullptr, x, 65536, 256, 256);
  k_ln2<<<16384, 256, 0, stream>>>(x1, ln2_s, ln2_b, ln2buf);
  k_mlp_fused<<<512, 256, 0, stream>>>(ln2buf, wm1, b1, wm2, b2, x1);
}

// Round 4
// 363.253 us; speedup vs baseline: 1.0201x; 1.0201x over previous
//
#include <hip/hip_runtime.h>
#include <hip/hip_bf16.h>
#include <math.h>

#define AS1 __attribute__((address_space(1)))
#define AS3 __attribute__((address_space(3)))

typedef __bf16  bf16x8 __attribute__((ext_vector_type(8)));
typedef float   f32x4  __attribute__((ext_vector_type(4)));
typedef __hip_bfloat16 bf16;

__device__ __forceinline__ void gload_lds16(const void* g, void* l) {
  __builtin_amdgcn_global_load_lds((const AS1 void*)g, (AS3 void*)l, 16, 0, 0);
}

// ---------------- weight conversion f32 -> bf16 ----------------
__global__ __launch_bounds__(256) void k_conv_weights(
    const float* __restrict__ qkvw, const float* __restrict__ projw,
    const float* __restrict__ w1, const float* __restrict__ w2,
    bf16* __restrict__ dst)
{
  int i = blockIdx.x * 256 + threadIdx.x;   // grid covers exactly 786432
  float v;
  if (i < 196608)       v = qkvw[i];
  else if (i < 262144)  v = projw[i - 196608];
  else if (i < 524288)  v = w1[i - 262144];
  else                  v = w2[i - 524288];
  dst[i] = __float2bfloat16(v);
}

// ---------------- rel-pos bias table: btab[h][n][m] ----------------
__global__ __launch_bounds__(256) void k_build_btab(
    const float* __restrict__ rel_bias, float* __restrict__ btab)
{
  int i = blockIdx.x * 256 + threadIdx.x;   // 32768
  int h = i >> 12, r = i & 4095, n = r >> 6, m = r & 63;
  int idx = ((n >> 3) - (m >> 3) + 7) * 15 + ((n & 7) - (m & 7) + 7);
  btab[i] = rel_bias[idx * 8 + h];
}

// ---------------- LN1 + roll(-4,-4) + window partition, f32 -> bf16 ----------------
__global__ __launch_bounds__(256) void k_ln1_window(
    const float* __restrict__ x, const float* __restrict__ sc,
    const float* __restrict__ bi, bf16* __restrict__ hout)
{
  int t = blockIdx.x * 4 + (threadIdx.x >> 6);
  int lane = threadIdx.x & 63;
  int win = t >> 6, nn = t & 63;
  int b = win >> 6, ww = win & 63;
  int ry = ((ww >> 3) << 3) + (nn >> 3);
  int rx = ((ww & 7) << 3) + (nn & 7);
  int sy = (ry + 4) & 63, sx = (rx + 4) & 63;
  const float* src = x + ((size_t)(((b << 6) + sy) << 6) + sx) * 256;
  f32x4 v = *(const f32x4*)(src + lane * 4);
  float s = v[0] + v[1] + v[2] + v[3];
  #pragma unroll
  for (int o = 1; o < 64; o <<= 1) s += __shfl_xor(s, o);
  float mu = s * (1.0f / 256.0f);
  float d0 = v[0]-mu, d1 = v[1]-mu, d2 = v[2]-mu, d3 = v[3]-mu;
  float q = d0*d0 + d1*d1 + d2*d2 + d3*d3;
  #pragma unroll
  for (int o = 1; o < 64; o <<= 1) q += __shfl_xor(q, o);
  float rstd = rsqrtf(q * (1.0f / 256.0f) + 1e-5f);
  int c = lane * 4;
  union { bf16 h[4]; uint2 u; } pk;
  pk.h[0] = __float2bfloat16(d0 * rstd * sc[c+0] + bi[c+0]);
  pk.h[1] = __float2bfloat16(d1 * rstd * sc[c+1] + bi[c+1]);
  pk.h[2] = __float2bfloat16(d2 * rstd * sc[c+2] + bi[c+2]);
  pk.h[3] = __float2bfloat16(d3 * rstd * sc[c+3] + bi[c+3]);
  *(uint2*)(hout + (size_t)t * 256 + c) = pk.u;
}

// ---------------- LN2 (pixel-major), f32 -> bf16 ----------------
__global__ __launch_bounds__(256) void k_ln2(
    const float* __restrict__ x1, const float* __restrict__ sc,
    const float* __restrict__ bi, bf16* __restrict__ out)
{
  int t = blockIdx.x * 4 + (threadIdx.x >> 6);
  int lane = threadIdx.x & 63;
  const float* src = x1 + (size_t)t * 256;
  f32x4 v = *(const f32x4*)(src + lane * 4);
  float s = v[0] + v[1] + v[2] + v[3];
  #pragma unroll
  for (int o = 1; o < 64; o <<= 1) s += __shfl_xor(s, o);
  float mu = s * (1.0f / 256.0f);
  float d0 = v[0]-mu, d1 = v[1]-mu, d2 = v[2]-mu, d3 = v[3]-mu;
  float q = d0*d0 + d1*d1 + d2*d2 + d3*d3;
  #pragma unroll
  for (int o = 1; o < 64; o <<= 1) q += __shfl_xor(q, o);
  float rstd = rsqrtf(q * (1.0f / 256.0f) + 1e-5f);
  int c = lane * 4;
  union { bf16 h[4]; uint2 u; } pk;
  pk.h[0] = __float2bfloat16(d0 * rstd * sc[c+0] + bi[c+0]);
  pk.h[1] = __float2bfloat16(d1 * rstd * sc[c+1] + bi[c+1]);
  pk.h[2] = __float2bfloat16(d2 * rstd * sc[c+2] + bi[c+2]);
  pk.h[3] = __float2bfloat16(d3 * rstd * sc[c+3] + bi[c+3]);
  *(uint2*)(out + (size_t)t * 256 + c) = pk.u;
}

// ============ A-resident N-streaming GEMM (K=256): C[M,N] = A@Bw^T + bias ============
// Block: 64 rows of A, full K=256 held in registers (per wave: 32 rows, 16 bf16x8).
// Streams N in chunks of 32 cols; B-chunk (32 x 256 bf16 = 16KB) double-buffered in
// LDS via global_load_lds with XOR-swizzle (pre-swizzled source, swizzled ds_read).
// Waves: (wr in {0,32}) x (wn in {0,16}). One barrier per chunk.
// EPI 0: store bf16 | EPI 1: GELU -> bf16 | EPI 2: proj remap + resid, f32 out
template<int EPI>
__global__ __launch_bounds__(256) void k_gemm_ar(
    const bf16* __restrict__ A, const bf16* __restrict__ Bw,
    const float* __restrict__ bias,
    float* __restrict__ Cf, bf16* __restrict__ Cb,
    const float* __restrict__ resid,
    int M, int N)
{
  __shared__ __align__(16) char lds[32768];   // 2 x 16KB dbuf

  const int tid = threadIdx.x;
  const int wid = tid >> 6;
  const int lane = tid & 63;
  const int l15 = lane & 15, lh = lane >> 4;
  const int wr = (wid >> 1) * 32;       // row half within 64-row block
  const int wn = (wid & 1) * 16;        // col half within 32-col chunk
  const int rowBase = blockIdx.x * 64;

  // ---- prologue: stage chunk 0, load A fragments (one-time) ----
  {
    #pragma unroll
    for (int i = 0; i < 4; ++i) {
      int off = (i * 256 + tid) * 16;             // 0..16383
      int r = off >> 9, cb = off & 511;
      int csw = cb ^ ((r & 7) << 4);
      gload_lds16((const char*)Bw + (size_t)r * 512 + csw, lds + off);
    }
  }
  bf16x8 af[2][8];
  #pragma unroll
  for (int m = 0; m < 2; ++m) {
    const bf16* arow = A + (size_t)(rowBase + wr + m * 16 + l15) * 256 + lh * 8;
    #pragma unroll
    for (int kk = 0; kk < 8; ++kk)
      af[m][kk] = *(const bf16x8*)(arow + kk * 32);
  }

  const int NC = N >> 5;                 // chunks of 32 cols
  // precompute row store addresses
  size_t rowAddr[2];
  #pragma unroll
  for (int m = 0; m < 2; ++m) {
    int row = rowBase + wr + m * 16 + l15;
    if (EPI == 2) {
      int win = row >> 6, nn = row & 63;
      int b = win >> 6, ww = win & 63;
      int ry = ((ww >> 3) << 3) + (nn >> 3);
      int rx = ((ww & 7) << 3) + (nn & 7);
      int fy = (ry + 4) & 63, fx = (rx + 4) & 63;
      rowAddr[m] = ((size_t)(((b << 6) + fy) << 6) + fx) * 256;
    } else {
      rowAddr[m] = (size_t)row * N;
    }
  }

  for (int s = 0; s < NC; ++s) {
    __syncthreads();                     // stage(s) complete; buf[(s+1)&1] free
    if (s + 1 < NC) {
      char* dst = lds + ((s + 1) & 1) * 16384;
      const char* srcB = (const char*)Bw + (size_t)(s + 1) * 32 * 512;
      #pragma unroll
      for (int i = 0; i < 4; ++i) {
        int off = (i * 256 + tid) * 16;
        int r = off >> 9, cb = off & 511;
        int csw = cb ^ ((r & 7) << 4);
        gload_lds16(srcB + (size_t)r * 512 + csw, dst + off);
      }
    }
    const char* buf = lds + (s & 1) * 16384;
    const int rB = wn + l15;
    const char* brow = buf + rB * 512;
    const int bxor = (rB & 7) << 4;

    f32x4 acc[2];
    acc[0] = (f32x4){0.f,0.f,0.f,0.f};
    acc[1] = (f32x4){0.f,0.f,0.f,0.f};
    #pragma unroll
    for (int kk = 0; kk < 8; ++kk) {
      bf16x8 wf = *(const bf16x8*)(brow + ((kk * 64 + lh * 16) ^ bxor));
      acc[0] = __builtin_amdgcn_mfma_f32_16x16x32_bf16(wf, af[0][kk], acc[0], 0, 0, 0);
      acc[1] = __builtin_amdgcn_mfma_f32_16x16x32_bf16(wf, af[1][kk], acc[1], 0, 0, 0);
    }

    // epilogue for this chunk: cols s*32 + wn + lh*4 .. +3, rows per m
    const int colb = s * 32 + wn + lh * 4;
    const f32x4 b4 = *(const f32x4*)(bias + colb);
    #pragma unroll
    for (int m = 0; m < 2; ++m) {
      f32x4 v4;
      #pragma unroll
      for (int j = 0; j < 4; ++j) v4[j] = acc[m][j] + b4[j];
      if (EPI == 0) {
        union { bf16 h[4]; uint2 u; } pk;
        #pragma unroll
        for (int j = 0; j < 4; ++j) pk.h[j] = __float2bfloat16(v4[j]);
        *(uint2*)(Cb + rowAddr[m] + colb) = pk.u;
      } else if (EPI == 1) {
        union { bf16 h[4]; uint2 u; } pk;
        #pragma unroll
        for (int j = 0; j < 4; ++j) {
          float v = v4[j];
          float w = fmaf(v * v, 0.1029434f, 2.3022083f);   // ln2-folded tanh-GELU
          float e = __builtin_amdgcn_exp2f(-v * w);
          float g = v * __builtin_amdgcn_rcpf(1.0f + e);
          pk.h[j] = __float2bfloat16(g);
        }
        *(uint2*)(Cb + rowAddr[m] + colb) = pk.u;
      } else {
        const f32x4 r4 = *(const f32x4*)(resid + rowAddr[m] + colb);
        f32x4 o4;
        #pragma unroll
        for (int j = 0; j < 4; ++j) o4[j] = v4[j] + r4[j];
        *(f32x4*)(Cf + rowAddr[m] + colb) = o4;
      }
    }
  }
}

// ---------------- classic tiled GEMM (for MLP2, K=1024): C = A@Bw^T ----------------
// EPI 3: Cf[addr] += val + bias (residual already in Cf), f32
#define BM 128
#define BN 128
#define BKK 64

__global__ __launch_bounds__(256) void k_gemm_bt3(
    const bf16* __restrict__ A, const bf16* __restrict__ Bw,
    const float* __restrict__ bias, float* __restrict__ Cf,
    int M, int N, int K)
{
  __shared__ __align__(16) char lds[BM*BKK*2 + BN*BKK*2];
  char* ldsA = lds;
  char* ldsB = lds + BM*BKK*2;

  const int tid = threadIdx.x;
  const int wid = tid >> 6;
  const int lane = tid & 63;
  const int l15 = lane & 15, lh = lane >> 4;
  const int rowBase = blockIdx.y * BM;
  const int colBase = blockIdx.x * BN;
  const int wr = (wid >> 1) * 64;
  const int wc = (wid & 1) * 64;

  f32x4 acc[4][4];
  #pragma unroll
  for (int i = 0; i < 4; ++i)
    #pragma unroll
    for (int j = 0; j < 4; ++j) acc[i][j] = (f32x4){0.f,0.f,0.f,0.f};

  for (int k0 = 0; k0 < K; k0 += BKK) {
    #pragma unroll
    for (int i = 0; i < 4; ++i) {
      int chunk = i * 4 + wid;
      int off = (chunk * 64 + lane) * 16;
      int r = off >> 7, cb = off & 127;
      int csw = cb ^ ((r & 7) << 4);
      gload_lds16((const char*)(A + (size_t)(rowBase + r) * K + k0) + csw, ldsA + chunk * 1024);
      gload_lds16((const char*)(Bw + (size_t)(colBase + r) * K + k0) + csw, ldsB + chunk * 1024);
    }
    __syncthreads();
    #pragma unroll
    for (int kk = 0; kk < BKK / 32; ++kk) {
      bf16x8 af[4], bfr[4];
      int kb = kk * 64 + lh * 16;
      #pragma unroll
      for (int m = 0; m < 4; ++m) {
        int rA = wr + m * 16 + l15;
        af[m] = *(const bf16x8*)(ldsA + rA * 128 + (kb ^ ((rA & 7) << 4)));
        int rB = wc + m * 16 + l15;
        bfr[m] = *(const bf16x8*)(ldsB + rB * 128 + (kb ^ ((rB & 7) << 4)));
      }
      #pragma unroll
      for (int m = 0; m < 4; ++m)
        #pragma unroll
        for (int n = 0; n < 4; ++n)
          acc[m][n] = __builtin_amdgcn_mfma_f32_16x16x32_bf16(bfr[n], af[m], acc[m][n], 0, 0, 0);
    }
    __syncthreads();
  }

  #pragma unroll
  for (int m = 0; m < 4; ++m) {
    size_t rowAddr = (size_t)(rowBase + wr + m * 16 + l15) * N;
    #pragma unroll
    for (int n = 0; n < 4; ++n) {
      const int colb = colBase + wc + n * 16 + lh * 4;
      const f32x4 b4 = *(const f32x4*)(bias + colb);
      f32x4* p = (f32x4*)(Cf + rowAddr + colb);
      f32x4 c = *p;
      #pragma unroll
      for (int j = 0; j < 4; ++j) c[j] += acc[m][n][j] + b4[j];
      *p = c;
    }
  }
}

// ---------------- attention: 1 wave per (window, head) ----------------
__global__ __launch_bounds__(256) void k_attn(
    const bf16* __restrict__ qkv, const float* __restrict__ btab,
    bf16* __restrict__ outp)
{
  __shared__ __align__(16) char smem[71680];
  float* sb = (float*)smem;                        // 64*64 f32 bias for this head
  const int tid = threadIdx.x, wid = tid >> 6, lane = tid & 63;
  const int l15 = lane & 15, lh = lane >> 4;
  const int h = blockIdx.x >> 8;
  const int win = ((blockIdx.x & 255) << 2) + wid;
  const int tb = win << 6;
  char* plw = smem + 16384 + wid * 9216;           // P: 64 rows x 144B
  char* vtw = smem + 16384 + 36864 + wid * 4608;   // Vt: 32 rows x 144B

  for (int i = tid; i < 4096; i += 256) sb[i] = btab[(h << 12) + i];
  __syncthreads();

  bf16x8 qf[4], kf[4];
  #pragma unroll
  for (int m = 0; m < 4; ++m) {
    size_t base = (size_t)(tb + m * 16 + l15) * 768 + h * 32 + lh * 8;
    qf[m] = *(const bf16x8*)(qkv + base);
    kf[m] = *(const bf16x8*)(qkv + base + 256);
  }
  f32x4 s[4][4];
  #pragma unroll
  for (int i = 0; i < 4; ++i)
    #pragma unroll
    for (int j = 0; j < 4; ++j) {
      s[i][j] = (f32x4){0.f,0.f,0.f,0.f};
      s[i][j] = __builtin_amdgcn_mfma_f32_16x16x32_bf16(qf[i], kf[j], s[i][j], 0, 0, 0);
    }

  #pragma unroll
  for (int it = 0; it < 32; ++it) {
    int idx = it * 64 + lane;
    int m = idx >> 5, d = idx & 31;
    bf16 vv = qkv[(size_t)(tb + m) * 768 + 512 + h * 32 + d];
    *(bf16*)(vtw + d * 144 + m * 2) = vv;
  }

  int ww = win & 63, wi = ww >> 3, wj = ww & 7;
  int labm[4];
  #pragma unroll
  for (int jf = 0; jf < 4; ++jf) {
    int m = jf * 16 + l15;
    int yy = wi * 8 + (m >> 3), xx = wj * 8 + (m & 7);
    labm[jf] = (yy < 56 ? 0 : (yy < 60 ? 1 : 2)) * 3 + (xx < 56 ? 0 : (xx < 60 ? 1 : 2));
  }
  float rsum[4][4];
  const float scale = 0.17677669529663687f;  // 1/sqrt(32)
  #pragma unroll
  for (int i = 0; i < 4; ++i) {
    #pragma unroll
    for (int j = 0; j < 4; ++j) {
      int n = i * 16 + lh * 4 + j;
      int yy = wi * 8 + (n >> 3), xx = wj * 8 + (n & 7);
      int labn = (yy < 56 ? 0 : (yy < 60 ? 1 : 2)) * 3 + (xx < 56 ? 0 : (xx < 60 ? 1 : 2));
      float vals[4]; float mx = -1e30f;
      #pragma unroll
      for (int jf = 0; jf < 4; ++jf) {
        int m = jf * 16 + l15;
        float v = s[i][jf][j] * scale + sb[(n << 6) + m];
        if (labn != labm[jf]) v -= 100.0f;
        vals[jf] = v; mx = fmaxf(mx, v);
      }
      #pragma unroll
      for (int o = 1; o < 16; o <<= 1) mx = fmaxf(mx, __shfl_xor(mx, o));
      float sum = 0.0f;
      #pragma unroll
      for (int jf = 0; jf < 4; ++jf) {
        float e = __expf(vals[jf] - mx);
        sum += e;
        *(bf16*)(plw + n * 144 + (jf * 16 + l15) * 2) = __float2bfloat16(e);
      }
      #pragma unroll
      for (int o = 1; o < 16; o <<= 1) sum += __shfl_xor(sum, o);
      rsum[i][j] = sum;
    }
  }
  __syncthreads();

  f32x4 o[4][2];
  #pragma unroll
  for (int i = 0; i < 4; ++i) { o[i][0] = (f32x4){0.f,0.f,0.f,0.f}; o[i][1] = (f32x4){0.f,0.f,0.f,0.f}; }
  #pragma unroll
  for (int kk = 0; kk < 2; ++kk) {
    bf16x8 pf[4], vf[2];
    #pragma unroll
    for (int i = 0; i < 4; ++i)
      pf[i] = *(const bf16x8*)(plw + (i * 16 + l15) * 144 + kk * 64 + lh * 16);
    #pragma unroll
    for (int df = 0; df < 2; ++df)
      vf[df] = *(const bf16x8*)(vtw + (df * 16 + l15) * 144 + kk * 64 + lh * 16);
    #pragma unroll
    for (int i = 0; i < 4; ++i)
      #pragma unroll
      for (int df = 0; df < 2; ++df)
        o[i][df] = __builtin_amdgcn_mfma_f32_16x16x32_bf16(pf[i], vf[df], o[i][df], 0, 0, 0);
  }
  #pragma unroll
  for (int i = 0; i < 4; ++i)
    #pragma unroll
    for (int df = 0; df < 2; ++df)
      #pragma unroll
      for (int j = 0; j < 4; ++j) {
        int n = i * 16 + lh * 4 + j;
        int d = df * 16 + l15;
        float v = o[i][df][j] / rsum[i][j];
        outp[(size_t)(tb + n) * 256 + h * 32 + d] = __float2bfloat16(v);
      }
}

// ---------------- launch ----------------
extern "C" void kernel_launch(void* const* d_in, const int* in_sizes, int n_in,
                              void* d_out, int out_size, void* d_ws, size_t ws_size,
                              hipStream_t stream) {
  (void)in_sizes; (void)n_in; (void)out_size; (void)ws_size;
  const float* x      = (const float*)d_in[0];
  const float* ln1_s  = (const float*)d_in[1];
  const float* ln1_b  = (const float*)d_in[2];
  const float* qkv_w  = (const float*)d_in[3];
  const float* qkv_b  = (const float*)d_in[4];
  const float* proj_w = (const float*)d_in[5];
  const float* proj_b = (const float*)d_in[6];
  const float* rel_b  = (const float*)d_in[7];
  const float* ln2_s  = (const float*)d_in[8];
  const float* ln2_b  = (const float*)d_in[9];
  const float* w1     = (const float*)d_in[10];
  const float* b1     = (const float*)d_in[11];
  const float* w2     = (const float*)d_in[12];
  const float* b2     = (const float*)d_in[13];

  char* ws = (char*)d_ws;
  bf16*  wqkv  = (bf16*)(ws + 0);               // 196608 el
  bf16*  wproj = wqkv + 196608;                 // 65536 el
  bf16*  wm1   = wqkv + 262144;                 // 262144 el
  bf16*  wm2   = wqkv + 524288;                 // 262144 el
  float* btab  = (float*)(ws + 1572864);        // 32768 f32
  bf16*  hbuf  = (bf16*)(ws + 2097152);         // 65536x256 (34MB..)
  bf16*  qkvb  = (bf16*)(ws + 35651584);        // 65536x768 (34MB..134MB)
  bf16*  attnb = (bf16*)(ws + 136314880);       // 65536x256 (130MB..163MB)
  bf16*  ln2buf = hbuf;                         // reuse (h dead after QKV gemm)
  bf16*  actb  = qkvb;                          // 65536x1024 (qkv+attn dead after proj)
  float* x1    = (float*)d_out;                 // residual lives in d_out

  k_conv_weights<<<3072, 256, 0, stream>>>(qkv_w, proj_w, w1, w2, wqkv);
  k_build_btab<<<128, 256, 0, stream>>>(rel_b, btab);
  k_ln1_window<<<16384, 256, 0, stream>>>(x, ln1_s, ln1_b, hbuf);
  k_gemm_ar<0><<<1024, 256, 0, stream>>>(hbuf, wqkv, qkv_b, nullptr, qkvb, nullptr, 65536, 768);
  k_attn<<<2048, 256, 0, stream>>>(qkvb, btab, attnb);
  k_gemm_ar<2><<<1024, 256, 0, stream>>>(attnb, wproj, proj_b, x1, nullptr, x, 65536, 256);
  k_ln2<<<16384, 256, 0, stream>>>(x1, ln2_s, ln2_b, ln2buf);
  k_gemm_ar<1><<<1024, 256, 0, stream>>>(ln2buf, wm1, b1, nullptr, actb, nullptr, 65536, 1024);
  k_gemm_bt3<<<dim3(2, 512), 256, 0, stream>>>(actb, wm2, b2, x1, 65536, 256, 1024);
}